// Round 4
// baseline (1429.879 us; speedup 1.0000x reference)
//
#include <hip/hip_runtime.h>
#include <cstdint>

#define N_VOX   200000
#define N_PAIRS 100000
#define KK      27
#define INC     64
#define OUTC    64
#define BN_EPS  1e-5f

// Binning geometry
#define ROWS_PER_PART 250
#define NPART         800              // 800*250 = 200000 exactly
#define NBIN          (KK * NPART)     // 21600
#define BIN_CAP       224              // avg 125, ~9 sigma headroom
#define OVF_CAP       4096

typedef __attribute__((ext_vector_type(8))) short bf16x8;
typedef __attribute__((ext_vector_type(4))) float f32x4;

__device__ inline uint32_t cvt_pk_bf16(float lo, float hi) {
    uint32_t r;
    asm("v_cvt_pk_bf16_f32 %0, %1, %2" : "=v"(r) : "v"(lo), "v"(hi));
    return r;
}

__device__ inline bf16x8 pack_frag(float a, float b, float c, float d,
                                   float e, float f, float g, float h) {
    union { uint32_t u[4]; bf16x8 v; } cv;
    cv.u[0] = cvt_pk_bf16(a, b);
    cv.u[1] = cvt_pk_bf16(c, d);
    cv.u[2] = cvt_pk_bf16(e, f);
    cv.u[3] = cvt_pk_bf16(g, h);
    return cv.v;
}

// ---------------------------------------------------------------------------
// Pre-pack w into bf16 B-fragment layout: frag fid=(k*4+n)*2+kk, lane l holds
// B[kbase + (l>>4)*8 + j][n*16 + (l&15)], stored as uint4 at wp[fid*64 + l].
// ---------------------------------------------------------------------------
__global__ __launch_bounds__(256) void pack_w(
    const float* __restrict__ w, uint4* __restrict__ wp)
{
    const int tid = blockIdx.x * blockDim.x + threadIdx.x;
    if (tid >= KK * 8 * 64) return;
    const int lane = tid & 63;
    const int fid  = tid >> 6;
    const int k    = fid >> 3;
    const int n    = (fid & 7) >> 1;
    const int kk   = fid & 1;
    const int row  = lane & 15;
    const int kg   = lane >> 4;
    const int kbase = kk * 32 + kg * 8;

    const float* bp = w + (size_t)k * (INC * OUTC) + (size_t)kbase * OUTC + n * 16 + row;
    bf16x8 f = pack_frag(bp[0*OUTC], bp[1*OUTC], bp[2*OUTC], bp[3*OUTC],
                         bp[4*OUTC], bp[5*OUTC], bp[6*OUTC], bp[7*OUTC]);
    union { bf16x8 v; uint4 u; } cv; cv.v = f;
    wp[(size_t)fid * 64 + lane] = cv.u;
}

// ---------------------------------------------------------------------------
// Bin the 2.7M (k,pair) entries into fixed-capacity (k,part) bins.
// Record = in_idx (18 bits) | local_row << 18 (8 bits).
// ---------------------------------------------------------------------------
__global__ __launch_bounds__(256) void scatter_pairs(
    const int* __restrict__ kin, const int* __restrict__ kout,
    uint32_t* __restrict__ cnt, uint32_t* __restrict__ bins,
    uint32_t* __restrict__ ovf_cnt, uint32_t* __restrict__ ovf)
{
    const int total = KK * N_PAIRS;
    for (int idx = blockIdx.x * blockDim.x + threadIdx.x; idx < total;
         idx += gridDim.x * blockDim.x) {
        const int k   = idx / N_PAIRS;
        const int out = kout[idx];
        const int in  = kin[idx];
        const int part  = out / ROWS_PER_PART;
        const int local = out - part * ROWS_PER_PART;
        const int bin   = k * NPART + part;
        const uint32_t pos = atomicAdd(&cnt[bin], 1u);
        if (pos < BIN_CAP) {
            bins[(size_t)bin * BIN_CAP + pos] = (uint32_t)in | ((uint32_t)local << 18);
        } else {
            const uint32_t p2 = atomicAdd(ovf_cnt, 1u);
            if (p2 < OVF_CAP) ovf[p2] = (uint32_t)idx;
        }
    }
}

// ---------------------------------------------------------------------------
// Binned conv: block = one output partition (250 rows in LDS). 8 waves pull
// (k,chunk) work items from an LDS queue; MFMA as before; scatter goes to
// LDS atomics; one coalesced flush at the end. No global atomics.
// ---------------------------------------------------------------------------
__global__ __launch_bounds__(512, 4) void conv_binned(
    const float* __restrict__ x, const uint4* __restrict__ wp,
    const uint32_t* __restrict__ cnt, const uint32_t* __restrict__ bins,
    float* __restrict__ y)
{
    __shared__ float yloc[ROWS_PER_PART * OUTC];   // 64000 B
    __shared__ int sh_cnt[KK];
    __shared__ int sh_pre[KK + 1];
    __shared__ uint32_t sh_cursor;

    const int tid  = threadIdx.x;
    const int lane = tid & 63;
    const int row  = lane & 15;
    const int kg   = lane >> 4;
    const int part = blockIdx.x;

    // zero the partition accumulator
    for (int i = tid; i < ROWS_PER_PART * OUTC; i += 512) yloc[i] = 0.f;
    if (tid < KK) {
        const uint32_t c = cnt[tid * NPART + part];
        sh_cnt[tid] = (int)(c < BIN_CAP ? c : BIN_CAP);
    }
    if (tid == 0) sh_cursor = 0;
    __syncthreads();
    if (tid == 0) {
        int s = 0;
        for (int i = 0; i < KK; ++i) { sh_pre[i] = s; s += (sh_cnt[i] + 15) >> 4; }
        sh_pre[KK] = s;
    }
    __syncthreads();
    const int total_chunks = sh_pre[KK];

    int kcur = -1;
    bf16x8 bfrag[4][2];

    for (;;) {
        uint32_t c;
        if (lane == 0) c = atomicAdd(&sh_cursor, 1u);
        c = (uint32_t)__shfl((int)c, 0);
        if ((int)c >= total_chunks) break;

        // locate (k, chunk)
        int k = 0;
        while ((int)c >= sh_pre[k + 1]) ++k;
        const int chunk = (int)c - sh_pre[k];

        if (k != kcur) {
            #pragma unroll
            for (int n = 0; n < 4; ++n) {
                #pragma unroll
                for (int kk = 0; kk < 2; ++kk) {
                    union { uint4 u; bf16x8 v; } cv;
                    cv.u = wp[(size_t)((k * 4 + n) * 2 + kk) * 64 + lane];
                    bfrag[n][kk] = cv.v;
                }
            }
            kcur = k;
        }

        const uint32_t* base = bins + (size_t)(k * NPART + part) * BIN_CAP;
        const int e0    = chunk * 16;
        const int count = min(16, sh_cnt[k] - e0);

        // gather indices
        const uint32_t rec_r = base[e0 + row];
        int in_idx = (int)(rec_r & 0x3FFFFu);
        in_idx = min(in_idx, N_VOX - 1);                     // clamp garbage tail recs
        const uint4 rec4 = *(const uint4*)(base + e0 + kg * 4);

        // A fragments
        const float* xr = x + (size_t)in_idx * INC + kg * 8;
        bf16x8 afrag[2];
        #pragma unroll
        for (int kk = 0; kk < 2; ++kk) {
            const f32x4 a0 = *(const f32x4*)(xr + kk * 32);
            const f32x4 a1 = *(const f32x4*)(xr + kk * 32 + 4);
            afrag[kk] = pack_frag(a0.x, a0.y, a0.z, a0.w, a1.x, a1.y, a1.z, a1.w);
        }

        f32x4 acc[4] = {{0,0,0,0},{0,0,0,0},{0,0,0,0},{0,0,0,0}};
        #pragma unroll
        for (int n = 0; n < 4; ++n) {
            acc[n] = __builtin_amdgcn_mfma_f32_16x16x32_bf16(afrag[0], bfrag[n][0], acc[n], 0, 0, 0);
            acc[n] = __builtin_amdgcn_mfma_f32_16x16x32_bf16(afrag[1], bfrag[n][1], acc[n], 0, 0, 0);
        }

        // LDS scatter: D row j of kg group -> pair rel = kg*4+j
        const uint32_t recj[4] = {rec4.x, rec4.y, rec4.z, rec4.w};
        #pragma unroll
        for (int j = 0; j < 4; ++j) {
            const int rel = kg * 4 + j;
            if (rel < count) {
                const int local = (int)(recj[j] >> 18);
                float* lb = &yloc[local * OUTC + row];
                atomicAdd(lb + 0,  acc[0][j]);
                atomicAdd(lb + 16, acc[1][j]);
                atomicAdd(lb + 32, acc[2][j]);
                atomicAdd(lb + 48, acc[3][j]);
            }
        }
    }

    __syncthreads();
    // coalesced flush: rows [part*250, part*250+250)
    float* yg = y + (size_t)part * ROWS_PER_PART * OUTC;
    for (int i = tid; i < ROWS_PER_PART * OUTC; i += 512) yg[i] = yloc[i];
}

// ---------------------------------------------------------------------------
// Overflow fixup (normally 0 entries): direct matvec + global atomic.
// ---------------------------------------------------------------------------
__global__ void ovf_fix(
    const float* __restrict__ x, const float* __restrict__ w,
    const int* __restrict__ kin, const int* __restrict__ kout,
    const uint32_t* __restrict__ ovf_cnt, const uint32_t* __restrict__ ovf,
    float* __restrict__ y)
{
    const int t = threadIdx.x;                 // 64 threads, t = channel
    const int n = (int)min(*ovf_cnt, (uint32_t)OVF_CAP);
    for (int i = 0; i < n; ++i) {
        const int idx = (int)ovf[i];
        const int k   = idx / N_PAIRS;
        const int in  = kin[idx];
        const int out = kout[idx];
        float acc = 0.f;
        for (int d = 0; d < INC; ++d)
            acc = fmaf(x[(size_t)in * INC + d], w[(size_t)k * INC * OUTC + d * OUTC + t], acc);
        unsafeAtomicAdd(&y[(size_t)out * OUTC + t], acc);
    }
}

// ---------------------------------------------------------------------------
// BN stats / finalize / apply (f32, y in d_out)
// ---------------------------------------------------------------------------
__global__ __launch_bounds__(256) void bn_reduce(
    const float* __restrict__ y, float* __restrict__ stats)
{
    __shared__ float s_sum[256];
    __shared__ float s_sq[256];

    const int c = threadIdx.x & 63;
    const int row0 = (blockIdx.x * blockDim.x + threadIdx.x) >> 6;
    const int rstride = (gridDim.x * blockDim.x) >> 6;

    float s = 0.f, ss = 0.f;
    for (int r = row0; r < N_VOX; r += rstride) {
        const float v = y[(size_t)r * OUTC + c];
        s += v;
        ss += v * v;
    }
    s_sum[threadIdx.x] = s;
    s_sq[threadIdx.x]  = ss;
    __syncthreads();

    if (threadIdx.x < 64) {
        const float ts  = (s_sum[c] + s_sum[64 + c]) + (s_sum[128 + c] + s_sum[192 + c]);
        const float tss = (s_sq[c]  + s_sq[64 + c])  + (s_sq[128 + c]  + s_sq[192 + c]);
        atomicAdd(&stats[c], ts);
        atomicAdd(&stats[64 + c], tss);
    }
}

__global__ void bn_finalize(
    const float* __restrict__ stats, const float* __restrict__ gamma,
    const float* __restrict__ beta, float* __restrict__ coef)
{
    const int c = threadIdx.x;
    if (c < 64) {
        const float inv_n = 1.0f / (float)N_VOX;
        const float mean  = stats[c] * inv_n;
        const float var   = stats[64 + c] * inv_n - mean * mean;
        const float scale = gamma[c] * rsqrtf(var + BN_EPS);
        coef[c]      = scale;
        coef[64 + c] = beta[c] - mean * scale;
    }
}

__global__ __launch_bounds__(256) void bn_apply(
    float* __restrict__ y, const float* __restrict__ coef)
{
    const size_t total4 = (size_t)N_VOX * OUTC / 4;
    size_t i = (size_t)blockIdx.x * blockDim.x + threadIdx.x;
    const size_t stride = (size_t)gridDim.x * blockDim.x;

    const int c0 = (int)((i * 4) & 63);
    const float sc0 = coef[c0 + 0], sh0 = coef[64 + c0 + 0];
    const float sc1 = coef[c0 + 1], sh1 = coef[64 + c0 + 1];
    const float sc2 = coef[c0 + 2], sh2 = coef[64 + c0 + 2];
    const float sc3 = coef[c0 + 3], sh3 = coef[64 + c0 + 3];

    float4* y4 = (float4*)y;
    for (; i < total4; i += stride) {
        float4 v = y4[i];
        v.x = fmaxf(0.f, fmaf(v.x, sc0, sh0));
        v.y = fmaxf(0.f, fmaf(v.y, sc1, sh1));
        v.z = fmaxf(0.f, fmaf(v.z, sc2, sh2));
        v.w = fmaxf(0.f, fmaf(v.w, sc3, sh3));
        y4[i] = v;
    }
}

// ============================ f32 fallback conv ============================
__global__ __launch_bounds__(256) void conv_mfma(
    const float* __restrict__ x, const float* __restrict__ w,
    const int* __restrict__ kin, const int* __restrict__ kout,
    float* __restrict__ y)
{
    const int lane = threadIdx.x & 63;
    const int wid  = threadIdx.x >> 6;
    const int k    = blockIdx.y;
    const int row  = lane & 15;
    const int kg   = lane >> 4;

    const float* wk = w + (size_t)k * (INC * OUTC);

    bf16x8 bfrag[4][2];
    #pragma unroll
    for (int n = 0; n < 4; ++n) {
        #pragma unroll
        for (int kk = 0; kk < 2; ++kk) {
            const int kbase = kk * 32 + kg * 8;
            const float* bp = wk + (size_t)kbase * OUTC + n * 16 + row;
            bfrag[n][kk] = pack_frag(bp[0*OUTC], bp[1*OUTC], bp[2*OUTC], bp[3*OUTC],
                                     bp[4*OUTC], bp[5*OUTC], bp[6*OUTC], bp[7*OUTC]);
        }
    }

    const int* kin_k  = kin  + (size_t)k * N_PAIRS;
    const int* kout_k = kout + (size_t)k * N_PAIRS;

    const int NCHUNK = N_PAIRS / 16;
    const int nwaves = gridDim.x * 4;

    for (int ch = blockIdx.x * 4 + wid; ch < NCHUNK; ch += nwaves) {
        const int e0 = ch * 16;
        const int in_idx = kin_k[e0 + row];
        const int4 oi = *(const int4*)(kout_k + e0 + kg * 4);

        const float* xr = x + (size_t)in_idx * INC + kg * 8;
        bf16x8 afrag[2];
        #pragma unroll
        for (int kk = 0; kk < 2; ++kk) {
            const f32x4 a0 = *(const f32x4*)(xr + kk * 32);
            const f32x4 a1 = *(const f32x4*)(xr + kk * 32 + 4);
            afrag[kk] = pack_frag(a0.x, a0.y, a0.z, a0.w, a1.x, a1.y, a1.z, a1.w);
        }

        f32x4 acc[4] = {{0,0,0,0},{0,0,0,0},{0,0,0,0},{0,0,0,0}};
        #pragma unroll
        for (int n = 0; n < 4; ++n) {
            acc[n] = __builtin_amdgcn_mfma_f32_16x16x32_bf16(afrag[0], bfrag[n][0], acc[n], 0, 0, 0);
            acc[n] = __builtin_amdgcn_mfma_f32_16x16x32_bf16(afrag[1], bfrag[n][1], acc[n], 0, 0, 0);
        }

        const int orow[4] = {oi.x, oi.y, oi.z, oi.w};
        #pragma unroll
        for (int j = 0; j < 4; ++j) {
            float* base = y + (size_t)orow[j] * OUTC + row;
            unsafeAtomicAdd(base + 0,  acc[0][j]);
            unsafeAtomicAdd(base + 16, acc[1][j]);
            unsafeAtomicAdd(base + 32, acc[2][j]);
            unsafeAtomicAdd(base + 48, acc[3][j]);
        }
    }
}

extern "C" void kernel_launch(void* const* d_in, const int* in_sizes, int n_in,
                              void* d_out, int out_size, void* d_ws, size_t ws_size,
                              hipStream_t stream)
{
    const float* x     = (const float*)d_in[0];
    const float* w     = (const float*)d_in[1];
    const float* gamma = (const float*)d_in[2];
    const float* beta  = (const float*)d_in[3];
    const int*   kin   = (const int*)d_in[4];
    const int*   kout  = (const int*)d_in[5];

    float* y = (float*)d_out;

    // ws layout
    const size_t off_cnt   = 0;                                  // 21600 u32
    const size_t off_ovfc  = 86400;                              // u32 + pad
    const size_t off_ovf   = 86464;                              // 4096 u32
    const size_t off_stats = 102912;                             // 128 f32
    const size_t off_coef  = 103424;                             // 128 f32
    const size_t off_wp    = 104448;                             // 13824 * 16B
    const size_t off_bins  = 325632;                             // 21600*224 u32
    const size_t need      = off_bins + (size_t)NBIN * BIN_CAP * 4;   // ~19.7 MB

    if (ws_size >= need) {
        uint32_t* cnt     = (uint32_t*)((char*)d_ws + off_cnt);
        uint32_t* ovfc    = (uint32_t*)((char*)d_ws + off_ovfc);
        uint32_t* ovf     = (uint32_t*)((char*)d_ws + off_ovf);
        float*    stats   = (float*)((char*)d_ws + off_stats);
        float*    coef    = (float*)((char*)d_ws + off_coef);
        uint4*    wp      = (uint4*)((char*)d_ws + off_wp);
        uint32_t* bins    = (uint32_t*)((char*)d_ws + off_bins);

        // zero cnt + ovf_cnt + ovf + stats in one shot
        hipMemsetAsync((char*)d_ws, 0, off_coef + 512, stream);

        pack_w<<<54, 256, 0, stream>>>(w, wp);
        scatter_pairs<<<2048, 256, 0, stream>>>(kin, kout, cnt, bins, ovfc, ovf);
        conv_binned<<<NPART, 512, 0, stream>>>(x, wp, cnt, bins, y);
        ovf_fix<<<1, 64, 0, stream>>>(x, w, kin, kout, ovfc, ovf, y);
        bn_reduce<<<512, 256, 0, stream>>>(y, stats);
        bn_finalize<<<1, 64, 0, stream>>>(stats, gamma, beta, coef);
        bn_apply<<<2048, 256, 0, stream>>>(y, coef);
    } else {
        // fallback: global-atomic path
        float* stats = (float*)d_ws;
        float* coef  = stats + 128;

        hipMemsetAsync(y, 0, (size_t)N_VOX * OUTC * sizeof(float), stream);
        hipMemsetAsync(stats, 0, 128 * sizeof(float), stream);

        conv_mfma<<<dim3(64, KK), 256, 0, stream>>>(x, w, kin, kout, y);
        bn_reduce<<<512, 256, 0, stream>>>(y, stats);
        bn_finalize<<<1, 64, 0, stream>>>(stats, gamma, beta, coef);
        bn_apply<<<2048, 256, 0, stream>>>(y, coef);
    }
}

// Round 5
// 1184.253 us; speedup vs baseline: 1.2074x; 1.2074x over previous
//
#include <hip/hip_runtime.h>
#include <cstdint>

#define N_VOX   200000
#define N_PAIRS 100000
#define KK      27
#define INC     64
#define OUTC    64
#define BN_EPS  1e-5f

// Binning geometry: partition output rows into chunks of 128 (part = row >> 7)
#define ROWS_PER_PART 128
#define NPART         1563             // ceil(200000/128), 1563*128 = 200064
#define NBIN          (KK * NPART)     // 42201
#define BIN_CAP       112              // avg 64, sigma 8 -> +6 sigma
#define OVF_CAP       4096

typedef __attribute__((ext_vector_type(8))) short bf16x8;
typedef __attribute__((ext_vector_type(4))) float f32x4;

__device__ inline uint32_t cvt_pk_bf16(float lo, float hi) {
    uint32_t r;
    asm("v_cvt_pk_bf16_f32 %0, %1, %2" : "=v"(r) : "v"(lo), "v"(hi));
    return r;
}

__device__ inline bf16x8 pack_frag(float a, float b, float c, float d,
                                   float e, float f, float g, float h) {
    union { uint32_t u[4]; bf16x8 v; } cv;
    cv.u[0] = cvt_pk_bf16(a, b);
    cv.u[1] = cvt_pk_bf16(c, d);
    cv.u[2] = cvt_pk_bf16(e, f);
    cv.u[3] = cvt_pk_bf16(g, h);
    return cv.v;
}

__device__ inline bf16x8 as_frag(uint4 u) {
    union { uint4 u; bf16x8 v; } cv; cv.u = u; return cv.v;
}

// ---------------------------------------------------------------------------
// Pre-pack w into bf16 B-fragment layout: frag fid=(k*4+n)*2+kk, lane l holds
// B[kbase + (l>>4)*8 + j][n*16 + (l&15)], stored as uint4 at wp[fid*64 + l].
// ---------------------------------------------------------------------------
__global__ __launch_bounds__(256) void pack_w(
    const float* __restrict__ w, uint4* __restrict__ wp)
{
    const int tid = blockIdx.x * blockDim.x + threadIdx.x;
    if (tid >= KK * 8 * 64) return;
    const int lane = tid & 63;
    const int fid  = tid >> 6;
    const int k    = fid >> 3;
    const int n    = (fid & 7) >> 1;
    const int kk   = fid & 1;
    const int row  = lane & 15;
    const int kg   = lane >> 4;
    const int kbase = kk * 32 + kg * 8;

    const float* bp = w + (size_t)k * (INC * OUTC) + (size_t)kbase * OUTC + n * 16 + row;
    bf16x8 f = pack_frag(bp[0*OUTC], bp[1*OUTC], bp[2*OUTC], bp[3*OUTC],
                         bp[4*OUTC], bp[5*OUTC], bp[6*OUTC], bp[7*OUTC]);
    union { bf16x8 v; uint4 u; } cv; cv.v = f;
    wp[(size_t)fid * 64 + lane] = cv.u;
}

// ---------------------------------------------------------------------------
// Bin the 2.7M (k,pair) entries into fixed-capacity (k,part) bins.
// Record = in_idx (18 bits) | local_row << 18 (7 bits). blockIdx.y = k.
// ---------------------------------------------------------------------------
__global__ __launch_bounds__(256) void scatter_pairs(
    const int* __restrict__ kin, const int* __restrict__ kout,
    uint32_t* __restrict__ cnt, uint32_t* __restrict__ bins,
    uint32_t* __restrict__ ovf_cnt, uint32_t* __restrict__ ovf)
{
    const int k = blockIdx.y;
    const int i = blockIdx.x * blockDim.x + threadIdx.x;
    if (i >= N_PAIRS) return;
    const int idx = k * N_PAIRS + i;
    const int out = kout[idx];
    const int in  = kin[idx];
    const int part  = out >> 7;
    const int local = out & 127;
    const int bin   = k * NPART + part;
    const uint32_t pos = atomicAdd(&cnt[bin], 1u);
    if (pos < BIN_CAP) {
        bins[(size_t)bin * BIN_CAP + pos] = (uint32_t)in | ((uint32_t)local << 18);
    } else {
        const uint32_t p2 = atomicAdd(ovf_cnt, 1u);
        if (p2 < OVF_CAP) ovf[p2] = (uint32_t)idx;
    }
}

// ---------------------------------------------------------------------------
// Binned conv: block = one 128-row output partition held in LDS. Wave wid
// statically owns k = wid, wid+8, ... and ALL chunks of that k. B-fragments
// in 8 named uint4 regs (SROA-proof), accumulators in 4 named f32x4.
// Scatter = ds_add_f32; one coalesced store-flush at the end. No global
// atomics, no work queue, no barriers in the k-loop.
// ---------------------------------------------------------------------------
__global__ __launch_bounds__(512) void conv_part(
    const float* __restrict__ x, const uint4* __restrict__ wp,
    const uint32_t* __restrict__ cnt, const uint32_t* __restrict__ bins,
    float* __restrict__ y)
{
    __shared__ float yloc[ROWS_PER_PART * OUTC];    // 32768 B
    __shared__ int sh_cnt[KK];

    const int tid  = threadIdx.x;
    const int lane = tid & 63;
    const int wid  = tid >> 6;            // 0..7
    const int row  = lane & 15;
    const int kg   = lane >> 4;
    const int part = blockIdx.x;

    {
        float4 z = {0.f, 0.f, 0.f, 0.f};
        float4* p = (float4*)yloc;
        #pragma unroll
        for (int i = 0; i < 4; ++i) p[tid + i * 512] = z;
    }
    if (tid < KK) {
        const uint32_t c = cnt[tid * NPART + part];
        sh_cnt[tid] = (int)(c < BIN_CAP ? c : BIN_CAP);
    }
    __syncthreads();

    for (int k = wid; k < KK; k += 8) {
        const int cntk = sh_cnt[k];
        if (cntk == 0) continue;

        // B fragments for this k: 8 named regs, unconditional load (L2-hot)
        const size_t fb = (size_t)(k * 8) * 64 + lane;
        const uint4 b0 = wp[fb];        const uint4 b1 = wp[fb + 64];
        const uint4 b2 = wp[fb + 128];  const uint4 b3 = wp[fb + 192];
        const uint4 b4 = wp[fb + 256];  const uint4 b5 = wp[fb + 320];
        const uint4 b6 = wp[fb + 384];  const uint4 b7 = wp[fb + 448];

        const uint32_t* base = bins + (size_t)(k * NPART + part) * BIN_CAP;
        const int nch = (cntk + 15) >> 4;

        for (int ch = 0; ch < nch; ++ch) {
            const int e0 = ch * 16;
            const int count = cntk - e0;          // >=16 except tail chunk

            const uint32_t rec_r = base[e0 + row];
            int in_idx = (int)(rec_r & 0x3FFFFu);
            in_idx = min(in_idx, N_VOX - 1);      // clamp garbage tail recs
            const uint4 rec4 = *(const uint4*)(base + e0 + kg * 4);

            // A fragments
            const float* xr = x + (size_t)in_idx * INC + kg * 8;
            const f32x4 x00 = *(const f32x4*)(xr);
            const f32x4 x01 = *(const f32x4*)(xr + 4);
            const f32x4 x10 = *(const f32x4*)(xr + 32);
            const f32x4 x11 = *(const f32x4*)(xr + 36);
            const bf16x8 a0 = pack_frag(x00.x, x00.y, x00.z, x00.w,
                                        x01.x, x01.y, x01.z, x01.w);
            const bf16x8 a1 = pack_frag(x10.x, x10.y, x10.z, x10.w,
                                        x11.x, x11.y, x11.z, x11.w);

            f32x4 c0 = {0,0,0,0}, c1 = {0,0,0,0}, c2 = {0,0,0,0}, c3 = {0,0,0,0};
            c0 = __builtin_amdgcn_mfma_f32_16x16x32_bf16(a0, as_frag(b0), c0, 0, 0, 0);
            c0 = __builtin_amdgcn_mfma_f32_16x16x32_bf16(a1, as_frag(b1), c0, 0, 0, 0);
            c1 = __builtin_amdgcn_mfma_f32_16x16x32_bf16(a0, as_frag(b2), c1, 0, 0, 0);
            c1 = __builtin_amdgcn_mfma_f32_16x16x32_bf16(a1, as_frag(b3), c1, 0, 0, 0);
            c2 = __builtin_amdgcn_mfma_f32_16x16x32_bf16(a0, as_frag(b4), c2, 0, 0, 0);
            c2 = __builtin_amdgcn_mfma_f32_16x16x32_bf16(a1, as_frag(b5), c2, 0, 0, 0);
            c3 = __builtin_amdgcn_mfma_f32_16x16x32_bf16(a0, as_frag(b6), c3, 0, 0, 0);
            c3 = __builtin_amdgcn_mfma_f32_16x16x32_bf16(a1, as_frag(b7), c3, 0, 0, 0);

            // LDS scatter: D row j of kg group -> pair rel = kg*4+j
            const uint32_t r0 = rec4.x, r1 = rec4.y, r2 = rec4.z, r3 = rec4.w;
            #pragma unroll
            for (int j = 0; j < 4; ++j) {
                const uint32_t rj = (j == 0) ? r0 : (j == 1) ? r1 : (j == 2) ? r2 : r3;
                if (kg * 4 + j < count) {
                    const int local = (int)((rj >> 18) & 127u);
                    float* lb = &yloc[local * OUTC + row];
                    __hip_atomic_fetch_add(lb + 0,  c0[j], __ATOMIC_RELAXED, __HIP_MEMORY_SCOPE_WORKGROUP);
                    __hip_atomic_fetch_add(lb + 16, c1[j], __ATOMIC_RELAXED, __HIP_MEMORY_SCOPE_WORKGROUP);
                    __hip_atomic_fetch_add(lb + 32, c2[j], __ATOMIC_RELAXED, __HIP_MEMORY_SCOPE_WORKGROUP);
                    __hip_atomic_fetch_add(lb + 48, c3[j], __ATOMIC_RELAXED, __HIP_MEMORY_SCOPE_WORKGROUP);
                }
            }
        }
    }

    __syncthreads();
    // coalesced flush (store, not add): rows [part*128, part*128+128) ∩ [0,N_VOX)
    const int grow0 = part * ROWS_PER_PART;
    float4* yg = (float4*)(y + (size_t)grow0 * OUTC);
    const float4* yl = (const float4*)yloc;
    #pragma unroll
    for (int i = 0; i < 4; ++i) {
        const int i4 = tid + i * 512;              // < 2048
        if (grow0 + (i4 >> 4) < N_VOX) yg[i4] = yl[i4];
    }
}

// ---------------------------------------------------------------------------
// Overflow fixup (normally 0 entries): direct matvec + global atomic add.
// Must run AFTER conv_part's flush.
// ---------------------------------------------------------------------------
__global__ void ovf_fix(
    const float* __restrict__ x, const float* __restrict__ w,
    const int* __restrict__ kin, const int* __restrict__ kout,
    const uint32_t* __restrict__ ovf_cnt, const uint32_t* __restrict__ ovf,
    float* __restrict__ y)
{
    const int t = threadIdx.x;                 // 64 threads, t = channel
    const int n = (int)min(*ovf_cnt, (uint32_t)OVF_CAP);
    for (int i = 0; i < n; ++i) {
        const int idx = (int)ovf[i];
        const int k   = idx / N_PAIRS;
        const int in  = kin[idx];
        const int out = kout[idx];
        float acc = 0.f;
        for (int d = 0; d < INC; ++d)
            acc = fmaf(x[(size_t)in * INC + d], w[(size_t)k * INC * OUTC + d * OUTC + t], acc);
        unsafeAtomicAdd(&y[(size_t)out * OUTC + t], acc);
    }
}

// ---------------------------------------------------------------------------
// BN stats / finalize / apply (f32, y in d_out)
// ---------------------------------------------------------------------------
__global__ __launch_bounds__(256) void bn_reduce(
    const float* __restrict__ y, float* __restrict__ stats)
{
    __shared__ float s_sum[256];
    __shared__ float s_sq[256];

    const int c = threadIdx.x & 63;
    const int row0 = (blockIdx.x * blockDim.x + threadIdx.x) >> 6;
    const int rstride = (gridDim.x * blockDim.x) >> 6;

    float s = 0.f, ss = 0.f;
    for (int r = row0; r < N_VOX; r += rstride) {
        const float v = y[(size_t)r * OUTC + c];
        s += v;
        ss += v * v;
    }
    s_sum[threadIdx.x] = s;
    s_sq[threadIdx.x]  = ss;
    __syncthreads();

    if (threadIdx.x < 64) {
        const float ts  = (s_sum[c] + s_sum[64 + c]) + (s_sum[128 + c] + s_sum[192 + c]);
        const float tss = (s_sq[c]  + s_sq[64 + c])  + (s_sq[128 + c]  + s_sq[192 + c]);
        atomicAdd(&stats[c], ts);
        atomicAdd(&stats[64 + c], tss);
    }
}

__global__ void bn_finalize(
    const float* __restrict__ stats, const float* __restrict__ gamma,
    const float* __restrict__ beta, float* __restrict__ coef)
{
    const int c = threadIdx.x;
    if (c < 64) {
        const float inv_n = 1.0f / (float)N_VOX;
        const float mean  = stats[c] * inv_n;
        const float var   = stats[64 + c] * inv_n - mean * mean;
        const float scale = gamma[c] * rsqrtf(var + BN_EPS);
        coef[c]      = scale;
        coef[64 + c] = beta[c] - mean * scale;
    }
}

__global__ __launch_bounds__(256) void bn_apply(
    float* __restrict__ y, const float* __restrict__ coef)
{
    const size_t total4 = (size_t)N_VOX * OUTC / 4;
    size_t i = (size_t)blockIdx.x * blockDim.x + threadIdx.x;
    const size_t stride = (size_t)gridDim.x * blockDim.x;

    const int c0 = (int)((i * 4) & 63);
    const float sc0 = coef[c0 + 0], sh0 = coef[64 + c0 + 0];
    const float sc1 = coef[c0 + 1], sh1 = coef[64 + c0 + 1];
    const float sc2 = coef[c0 + 2], sh2 = coef[64 + c0 + 2];
    const float sc3 = coef[c0 + 3], sh3 = coef[64 + c0 + 3];

    float4* y4 = (float4*)y;
    for (; i < total4; i += stride) {
        float4 v = y4[i];
        v.x = fmaxf(0.f, fmaf(v.x, sc0, sh0));
        v.y = fmaxf(0.f, fmaf(v.y, sc1, sh1));
        v.z = fmaxf(0.f, fmaf(v.z, sc2, sh2));
        v.w = fmaxf(0.f, fmaf(v.w, sc3, sh3));
        y4[i] = v;
    }
}

// ============================ f32 fallback conv ============================
__global__ __launch_bounds__(256) void conv_mfma(
    const float* __restrict__ x, const float* __restrict__ w,
    const int* __restrict__ kin, const int* __restrict__ kout,
    float* __restrict__ y)
{
    const int lane = threadIdx.x & 63;
    const int wid  = threadIdx.x >> 6;
    const int k    = blockIdx.y;
    const int row  = lane & 15;
    const int kg   = lane >> 4;

    const float* wk = w + (size_t)k * (INC * OUTC);

    bf16x8 bfrag[4][2];
    #pragma unroll
    for (int n = 0; n < 4; ++n) {
        #pragma unroll
        for (int kk = 0; kk < 2; ++kk) {
            const int kbase = kk * 32 + kg * 8;
            const float* bp = wk + (size_t)kbase * OUTC + n * 16 + row;
            bfrag[n][kk] = pack_frag(bp[0*OUTC], bp[1*OUTC], bp[2*OUTC], bp[3*OUTC],
                                     bp[4*OUTC], bp[5*OUTC], bp[6*OUTC], bp[7*OUTC]);
        }
    }

    const int* kin_k  = kin  + (size_t)k * N_PAIRS;
    const int* kout_k = kout + (size_t)k * N_PAIRS;

    const int NCHUNK = N_PAIRS / 16;
    const int nwaves = gridDim.x * 4;

    for (int ch = blockIdx.x * 4 + wid; ch < NCHUNK; ch += nwaves) {
        const int e0 = ch * 16;
        const int in_idx = kin_k[e0 + row];
        const int4 oi = *(const int4*)(kout_k + e0 + kg * 4);

        const float* xr = x + (size_t)in_idx * INC + kg * 8;
        bf16x8 afrag[2];
        #pragma unroll
        for (int kk = 0; kk < 2; ++kk) {
            const f32x4 a0 = *(const f32x4*)(xr + kk * 32);
            const f32x4 a1 = *(const f32x4*)(xr + kk * 32 + 4);
            afrag[kk] = pack_frag(a0.x, a0.y, a0.z, a0.w, a1.x, a1.y, a1.z, a1.w);
        }

        f32x4 acc[4] = {{0,0,0,0},{0,0,0,0},{0,0,0,0},{0,0,0,0}};
        #pragma unroll
        for (int n = 0; n < 4; ++n) {
            acc[n] = __builtin_amdgcn_mfma_f32_16x16x32_bf16(afrag[0], bfrag[n][0], acc[n], 0, 0, 0);
            acc[n] = __builtin_amdgcn_mfma_f32_16x16x32_bf16(afrag[1], bfrag[n][1], acc[n], 0, 0, 0);
        }

        const int orow[4] = {oi.x, oi.y, oi.z, oi.w};
        #pragma unroll
        for (int j = 0; j < 4; ++j) {
            float* base = y + (size_t)orow[j] * OUTC + row;
            unsafeAtomicAdd(base + 0,  acc[0][j]);
            unsafeAtomicAdd(base + 16, acc[1][j]);
            unsafeAtomicAdd(base + 32, acc[2][j]);
            unsafeAtomicAdd(base + 48, acc[3][j]);
        }
    }
}

extern "C" void kernel_launch(void* const* d_in, const int* in_sizes, int n_in,
                              void* d_out, int out_size, void* d_ws, size_t ws_size,
                              hipStream_t stream)
{
    const float* x     = (const float*)d_in[0];
    const float* w     = (const float*)d_in[1];
    const float* gamma = (const float*)d_in[2];
    const float* beta  = (const float*)d_in[3];
    const int*   kin   = (const int*)d_in[4];
    const int*   kout  = (const int*)d_in[5];

    float* y = (float*)d_out;

    // ws layout
    const size_t off_cnt   = 0;                                   // 42201 u32
    const size_t off_ovfc  = 169000;
    const size_t off_ovf   = 169064;                              // 4096 u32
    const size_t off_stats = 185600;                              // 128 f32
    const size_t off_coef  = 186112;                              // 128 f32
    const size_t off_wp    = 186624;                              // 13824 * 16B
    const size_t off_bins  = off_wp + (size_t)KK * 8 * 64 * 16;   // 407808
    const size_t need      = off_bins + (size_t)NBIN * BIN_CAP * 4;  // ~19.3 MB

    if (ws_size >= need) {
        uint32_t* cnt     = (uint32_t*)((char*)d_ws + off_cnt);
        uint32_t* ovfc    = (uint32_t*)((char*)d_ws + off_ovfc);
        uint32_t* ovf     = (uint32_t*)((char*)d_ws + off_ovf);
        float*    stats   = (float*)((char*)d_ws + off_stats);
        float*    coef    = (float*)((char*)d_ws + off_coef);
        uint4*    wp      = (uint4*)((char*)d_ws + off_wp);
        uint32_t* bins    = (uint32_t*)((char*)d_ws + off_bins);

        // zero cnt + ovf_cnt + ovf + stats in one shot
        hipMemsetAsync((char*)d_ws, 0, off_coef, stream);

        pack_w<<<54, 256, 0, stream>>>(w, wp);
        scatter_pairs<<<dim3((N_PAIRS + 255) / 256, KK), 256, 0, stream>>>(
            kin, kout, cnt, bins, ovfc, ovf);
        conv_part<<<NPART, 512, 0, stream>>>(x, wp, cnt, bins, y);
        ovf_fix<<<1, 64, 0, stream>>>(x, w, kin, kout, ovfc, ovf, y);
        bn_reduce<<<512, 256, 0, stream>>>(y, stats);
        bn_finalize<<<1, 64, 0, stream>>>(stats, gamma, beta, coef);
        bn_apply<<<2048, 256, 0, stream>>>(y, coef);
    } else {
        // fallback: global-atomic path
        float* stats = (float*)d_ws;
        float* coef  = stats + 128;

        hipMemsetAsync(y, 0, (size_t)N_VOX * OUTC * sizeof(float), stream);
        hipMemsetAsync(stats, 0, 128 * sizeof(float), stream);

        conv_mfma<<<dim3(64, KK), 256, 0, stream>>>(x, w, kin, kout, y);
        bn_reduce<<<512, 256, 0, stream>>>(y, stats);
        bn_finalize<<<1, 64, 0, stream>>>(stats, gamma, beta, coef);
        bn_apply<<<2048, 256, 0, stream>>>(y, coef);
    }
}